// Round 1
// baseline (383.664 us; speedup 1.0000x reference)
//
#include <hip/hip_runtime.h>
#include <math.h>

#define BB 256
#define FF 1024
#define GG 512
#define SS 512
#define EE 256
#define PP 8
#define TT 256

__device__ __forceinline__ float sigmoidf_(float x) { return 1.0f / (1.0f + expf(-x)); }

// ---------------------------------------------------------------------------
// spk_id (argmax of one-hot mask) + gather sel0 = speaker0[b, spk_id[b], :]
// grid = B blocks, 256 threads
// ---------------------------------------------------------------------------
__global__ __launch_bounds__(256) void k_gather(const float* __restrict__ mask,
                                                const float* __restrict__ speaker0,
                                                int* __restrict__ spk,
                                                float* __restrict__ sel0) {
    int b = blockIdx.x;
    int tid = threadIdx.x;
    __shared__ int sid;
    if (tid == 0) {
        int best = 0;
        float bv = mask[b * PP];
        for (int p = 1; p < PP; ++p) {
            float v = mask[b * PP + p];
            if (v > bv) { bv = v; best = p; }
        }
        sid = best;
        spk[b] = best;
    }
    __syncthreads();
    int p = sid;
    const float* src = speaker0 + ((size_t)b * PP + p) * SS;
    sel0[(size_t)b * SS + tid]       = src[tid];
    sel0[(size_t)b * SS + tid + 256] = src[tid + 256];
}

// ---------------------------------------------------------------------------
// Generic C = A @ W[:, woff:woff+K].T (+bias | +=) ; A:(M,lda) W:(N,ldw) C:(M,N)
// 64x64 tile, 256 threads, 4x4 microtile, BK=16, fp32
// ---------------------------------------------------------------------------
__global__ __launch_bounds__(256) void k_mm(const float* __restrict__ A, int lda,
                                            const float* __restrict__ W, int ldw, int woff,
                                            float* __restrict__ C, int ldc,
                                            const float* __restrict__ bias, int accumulate,
                                            int K) {
    __shared__ float As[16][68];
    __shared__ float Ws[16][68];
    const int tid = threadIdx.x;
    const int bm = blockIdx.y * 64, bn = blockIdx.x * 64;
    const int tm = (tid >> 4) << 2;   // (tid/16)*4
    const int tn = (tid & 15) << 2;   // (tid%16)*4
    const int lr = tid >> 2;          // 0..63
    const int lc = (tid & 3) << 2;    // 0,4,8,12

    float acc[4][4] = {};

    for (int k0 = 0; k0 < K; k0 += 16) {
        float4 av = *(const float4*)(A + (size_t)(bm + lr) * lda + k0 + lc);
        float4 wv = *(const float4*)(W + (size_t)(bn + lr) * ldw + woff + k0 + lc);
        As[lc + 0][lr] = av.x; As[lc + 1][lr] = av.y; As[lc + 2][lr] = av.z; As[lc + 3][lr] = av.w;
        Ws[lc + 0][lr] = wv.x; Ws[lc + 1][lr] = wv.y; Ws[lc + 2][lr] = wv.z; Ws[lc + 3][lr] = wv.w;
        __syncthreads();
#pragma unroll
        for (int k = 0; k < 16; ++k) {
            float4 a4 = *(const float4*)&As[k][tm];
            float4 b4 = *(const float4*)&Ws[k][tn];
            float a_[4] = {a4.x, a4.y, a4.z, a4.w};
            float b_[4] = {b4.x, b4.y, b4.z, b4.w};
#pragma unroll
            for (int i = 0; i < 4; ++i)
#pragma unroll
                for (int j = 0; j < 4; ++j) acc[i][j] += a_[i] * b_[j];
        }
        __syncthreads();
    }

#pragma unroll
    for (int i = 0; i < 4; ++i) {
        int row = bm + tm + i;
#pragma unroll
        for (int j = 0; j < 4; ++j) {
            int col = bn + tn + j;
            size_t idx = (size_t)row * ldc + col;
            float v = acc[i][j];
            if (accumulate) C[idx] += v;
            else            C[idx] = v + (bias ? bias[col] : 0.0f);
        }
    }
}

// ---------------------------------------------------------------------------
// Attention: per-b block. scores[t] = <x_[b], gh[t,b,:]>, softmax over t,
// context[b,g] = sum_t alpha[t] * gh[t,b,g].  grid = B, 256 threads.
// ---------------------------------------------------------------------------
__global__ __launch_bounds__(256) void k_attn(const float* __restrict__ x_,
                                              const float* __restrict__ gh,
                                              float* __restrict__ context) {
    int b = blockIdx.x;
    int tid = threadIdx.x;
    __shared__ float xs[GG];
    __shared__ float s[TT];
    __shared__ float red[256];

    xs[tid]       = x_[(size_t)b * GG + tid];
    xs[tid + 256] = x_[(size_t)b * GG + tid + 256];
    __syncthreads();

    int wave = tid >> 6, lane = tid & 63;
    // pass 1: scores
    for (int t = wave * 64; t < wave * 64 + 64; ++t) {
        const float* row = gh + ((size_t)t * BB + b) * GG;
        float4 v1 = *(const float4*)&row[lane * 8];
        float4 v2 = *(const float4*)&row[lane * 8 + 4];
        float p = v1.x * xs[lane * 8 + 0] + v1.y * xs[lane * 8 + 1] +
                  v1.z * xs[lane * 8 + 2] + v1.w * xs[lane * 8 + 3] +
                  v2.x * xs[lane * 8 + 4] + v2.y * xs[lane * 8 + 5] +
                  v2.z * xs[lane * 8 + 6] + v2.w * xs[lane * 8 + 7];
#pragma unroll
        for (int off = 32; off; off >>= 1) p += __shfl_down(p, off);
        if (lane == 0) s[t] = p;
    }
    __syncthreads();

    // softmax over 256 scores; thread tid owns s[tid]
    float v = s[tid];
    red[tid] = v;
    __syncthreads();
    for (int off = 128; off; off >>= 1) {
        if (tid < off) red[tid] = fmaxf(red[tid], red[tid + off]);
        __syncthreads();
    }
    float m = red[0];
    __syncthreads();
    float e = expf(v - m);
    red[tid] = e;
    __syncthreads();
    for (int off = 128; off; off >>= 1) {
        if (tid < off) red[tid] += red[tid + off];
        __syncthreads();
    }
    float denom = red[0];
    __syncthreads();
    s[tid] = e / denom;
    __syncthreads();

    // pass 2: weighted sum
    float acc0 = 0.f, acc1 = 0.f;
    for (int t = 0; t < TT; ++t) {
        float a = s[t];
        const float* row = gh + ((size_t)t * BB + b) * GG;
        acc0 += a * row[tid];
        acc1 += a * row[tid + 256];
    }
    context[(size_t)b * GG + tid]       = acc0;
    context[(size_t)b * GG + tid + 256] = acc1;
}

// ---------------------------------------------------------------------------
// GRU elementwise combine: gi,gh:(B,3H), h:(B,H) -> out:(B,H)
// ---------------------------------------------------------------------------
__global__ __launch_bounds__(256) void k_gru(const float* __restrict__ gi,
                                             const float* __restrict__ gh,
                                             const float* __restrict__ h,
                                             float* __restrict__ out, int H) {
    int idx = blockIdx.x * 256 + threadIdx.x;
    int b = idx / H, j = idx - b * H;
    const float* gib = gi + (size_t)b * 3 * H;
    const float* ghb = gh + (size_t)b * 3 * H;
    float r = sigmoidf_(gib[j] + ghb[j]);
    float z = sigmoidf_(gib[H + j] + ghb[H + j]);
    float n = tanhf(gib[2 * H + j] + r * ghb[2 * H + j]);
    out[idx] = (1.0f - z) * n + z * h[idx];
}

// ---------------------------------------------------------------------------
// speaker output: speaker0 everywhere except selected rows get parties
// ---------------------------------------------------------------------------
__global__ __launch_bounds__(256) void k_speaker(const float* __restrict__ speaker0,
                                                 const float* __restrict__ parties,
                                                 const int* __restrict__ spk,
                                                 float* __restrict__ out) {
    int idx = blockIdx.x * 256 + threadIdx.x;   // over B*P*S
    int s = idx & (SS - 1);
    int p = (idx / SS) & (PP - 1);
    int b = idx / (SS * PP);
    float v = speaker0[idx];
    if (p == spk[b]) v = parties[(size_t)b * SS + s];
    out[idx] = v;
}

// ---------------------------------------------------------------------------
static inline void mm(hipStream_t st, const float* A, int lda,
                      const float* W, int ldw, int woff,
                      float* C, int N, int K, const float* bias, int acc) {
    dim3 g(N / 64, BB / 64);
    k_mm<<<g, 256, 0, st>>>(A, lda, W, ldw, woff, C, N, bias, acc, K);
}

extern "C" void kernel_launch(void* const* d_in, const int* in_sizes, int n_in,
                              void* d_out, int out_size, void* d_ws, size_t ws_size,
                              hipStream_t stream) {
    const float* feature_  = (const float*)d_in[0];
    const float* mask      = (const float*)d_in[1];
    const float* ghist     = (const float*)d_in[2];
    const float* speaker0  = (const float*)d_in[3];
    const float* emotion0  = (const float*)d_in[4];
    const float* Wg_ih     = (const float*)d_in[5];
    const float* Wg_hh     = (const float*)d_in[6];
    const float* bg_ih     = (const float*)d_in[7];
    const float* bg_hh     = (const float*)d_in[8];
    const float* Wp_ih     = (const float*)d_in[9];
    const float* Wp_hh     = (const float*)d_in[10];
    const float* bp_ih     = (const float*)d_in[11];
    const float* bp_hh     = (const float*)d_in[12];
    const float* We_ih     = (const float*)d_in[13];
    const float* We_hh     = (const float*)d_in[14];
    const float* be_ih     = (const float*)d_in[15];
    const float* be_hh     = (const float*)d_in[16];
    const float* attn_W    = (const float*)d_in[17];

    float* out = (float*)d_out;
    float* emotion_out = out;                     // (B,E)
    float* global_out  = out + (size_t)BB * EE;   // (B,G)
    float* speaker_out = global_out + (size_t)BB * GG;  // (B,P,S)

    float* ws = (float*)d_ws;
    int*   spk     = (int*)ws;                         // 256 ints
    float* sel0    = ws + 256;                         // B*S
    float* x_      = sel0 + (size_t)BB * SS;           // B*G
    float* ctx     = x_ + (size_t)BB * GG;             // B*G
    float* parties = ctx + (size_t)BB * GG;            // B*S
    float* gi_g    = parties + (size_t)BB * SS;        // B*3G
    float* gh_g    = gi_g + (size_t)BB * 3 * GG;       // B*3G
    float* gi_p    = gh_g + (size_t)BB * 3 * GG;       // B*3S
    float* gh_p    = gi_p + (size_t)BB * 3 * SS;       // B*3S
    float* gi_e    = gh_p + (size_t)BB * 3 * SS;       // B*3E
    float* gh_e    = gi_e + (size_t)BB * 3 * EE;       // B*3E

    const float* h_g = ghist + (size_t)(TT - 1) * BB * GG;  // global_history[-1]

    // gather
    k_gather<<<BB, 256, 0, stream>>>(mask, speaker0, spk, sel0);

    // global GRU: x = [feature_, sel0], h = global_history[-1]
    mm(stream, feature_, FF, Wg_ih, FF + SS, 0,  gi_g, 3 * GG, FF, bg_ih, 0);
    mm(stream, sel0,     SS, Wg_ih, FF + SS, FF, gi_g, 3 * GG, SS, nullptr, 1);
    mm(stream, h_g,      GG, Wg_hh, GG,      0,  gh_g, 3 * GG, GG, bg_hh, 0);
    k_gru<<<(BB * GG) / 256, 256, 0, stream>>>(gi_g, gh_g, h_g, global_out, GG);

    // attention
    mm(stream, feature_, FF, attn_W, FF, 0, x_, GG, FF, nullptr, 0);
    k_attn<<<BB, 256, 0, stream>>>(x_, ghist, ctx);

    // parties GRU (selected rows only): x = [feature_, ctx], h = sel0
    mm(stream, feature_, FF, Wp_ih, FF + GG, 0,  gi_p, 3 * SS, FF, bp_ih, 0);
    mm(stream, ctx,      GG, Wp_ih, FF + GG, FF, gi_p, 3 * SS, GG, nullptr, 1);
    mm(stream, sel0,     SS, Wp_hh, SS,      0,  gh_p, 3 * SS, SS, bp_hh, 0);
    k_gru<<<(BB * SS) / 256, 256, 0, stream>>>(gi_p, gh_p, sel0, parties, SS);

    // speaker output
    k_speaker<<<(BB * PP * SS) / 256, 256, 0, stream>>>(speaker0, parties, spk, speaker_out);

    // emotion GRU: x = parties, h = emotion0
    mm(stream, parties,  SS, We_ih, SS, 0, gi_e, 3 * EE, SS, be_ih, 0);
    mm(stream, emotion0, EE, We_hh, EE, 0, gh_e, 3 * EE, EE, be_hh, 0);
    k_gru<<<(BB * EE) / 256, 256, 0, stream>>>(gi_e, gh_e, emotion0, emotion_out, EE);
}

// Round 3
// 151.105 us; speedup vs baseline: 2.5391x; 2.5391x over previous
//
#include <hip/hip_runtime.h>
#include <math.h>

#define BB 256
#define FF 1024
#define GG 512
#define SS 512
#define EE 256
#define PP 8
#define TT 256

typedef __attribute__((ext_vector_type(8))) short bs8;     // 8 bf16
typedef __attribute__((ext_vector_type(4))) float f32x4;

__device__ __forceinline__ float sigmoidf_(float x) { return 1.0f / (1.0f + expf(-x)); }

__device__ __forceinline__ short f2bf(float f) {
    union { float f; unsigned u; } v; v.f = f;
    unsigned r = v.u + 0x7FFFu + ((v.u >> 16) & 1u);   // RNE
    return (short)(r >> 16);
}
__device__ __forceinline__ float bf2f(short h) {
    union { unsigned u; float f; } t; t.u = ((unsigned)(unsigned short)h) << 16; return t.f;
}

// ---------------------------------------------------------------------------
// Fused weight conversion fp32 -> bf16, all 7 weights into one bf16 slab.
// ---------------------------------------------------------------------------
#define W0E 2359296   // Wg_ih 1536x1536
#define W1E 786432    // Wg_hh 1536x512
#define W2E 2359296   // Wp_ih
#define W3E 786432    // Wp_hh
#define W4E 393216    // We_ih 768x512
#define W5E 196608    // We_hh 768x256
#define W6E 524288    // attn_W 512x1024
#define WTOT (W0E+W1E+W2E+W3E+W4E+W5E+W6E)

__global__ __launch_bounds__(256) void k_convw(const float* __restrict__ w0, const float* __restrict__ w1,
                                               const float* __restrict__ w2, const float* __restrict__ w3,
                                               const float* __restrict__ w4, const float* __restrict__ w5,
                                               const float* __restrict__ w6, short* __restrict__ dst) {
    long i = ((long)blockIdx.x * 256 + threadIdx.x) * 8;
    const float* src; long base;
    if      (i < W0E)                     { src = w0; base = 0; }
    else if (i < W0E+W1E)                 { src = w1; base = W0E; }
    else if (i < W0E+W1E+W2E)             { src = w2; base = W0E+W1E; }
    else if (i < W0E+W1E+W2E+W3E)         { src = w3; base = W0E+W1E+W2E; }
    else if (i < W0E+W1E+W2E+W3E+W4E)     { src = w4; base = W0E+W1E+W2E+W3E; }
    else if (i < W0E+W1E+W2E+W3E+W4E+W5E) { src = w5; base = W0E+W1E+W2E+W3E+W4E; }
    else                                  { src = w6; base = W0E+W1E+W2E+W3E+W4E+W5E; }
    long lo = i - base;
    float4 a = *(const float4*)(src + lo);
    float4 b = *(const float4*)(src + lo + 4);
    bs8 o;
    o[0]=f2bf(a.x); o[1]=f2bf(a.y); o[2]=f2bf(a.z); o[3]=f2bf(a.w);
    o[4]=f2bf(b.x); o[5]=f2bf(b.y); o[6]=f2bf(b.z); o[7]=f2bf(b.w);
    *(bs8*)(dst + i) = o;
}

// feature_ (B,F) fp32 -> bf16 into xg[:, :F] and xp[:, :F] (row stride 1536)
__global__ __launch_bounds__(256) void k_convf(const float* __restrict__ f,
                                               short* __restrict__ xg, short* __restrict__ xp) {
    int i = (blockIdx.x * 256 + threadIdx.x) * 8;
    int b = i >> 10, c = i & 1023;
    float4 a = *(const float4*)(f + i);
    float4 d = *(const float4*)(f + i + 4);
    bs8 o;
    o[0]=f2bf(a.x); o[1]=f2bf(a.y); o[2]=f2bf(a.z); o[3]=f2bf(a.w);
    o[4]=f2bf(d.x); o[5]=f2bf(d.y); o[6]=f2bf(d.z); o[7]=f2bf(d.w);
    *(bs8*)(xg + (size_t)b * 1536 + c) = o;
    *(bs8*)(xp + (size_t)b * 1536 + c) = o;
}

// generic fp32 -> bf16
__global__ __launch_bounds__(256) void k_conv(const float* __restrict__ src, short* __restrict__ dst, int n8) {
    int gid = blockIdx.x * 256 + threadIdx.x;
    if (gid >= n8) return;
    int i = gid * 8;
    float4 a = *(const float4*)(src + i);
    float4 b = *(const float4*)(src + i + 4);
    bs8 o;
    o[0]=f2bf(a.x); o[1]=f2bf(a.y); o[2]=f2bf(a.z); o[3]=f2bf(a.w);
    o[4]=f2bf(b.x); o[5]=f2bf(b.y); o[6]=f2bf(b.z); o[7]=f2bf(b.w);
    *(bs8*)(dst + i) = o;
}

// fp32 -> (hi, lo) bf16 split
__global__ __launch_bounds__(256) void k_convsplit(const float* __restrict__ src,
                                                   short* __restrict__ hi, short* __restrict__ lo, int n8) {
    int gid = blockIdx.x * 256 + threadIdx.x;
    if (gid >= n8) return;
    int i = gid * 8;
    float4 a = *(const float4*)(src + i);
    float4 b = *(const float4*)(src + i + 4);
    float v[8] = {a.x, a.y, a.z, a.w, b.x, b.y, b.z, b.w};
    bs8 h, l;
#pragma unroll
    for (int j = 0; j < 8; ++j) {
        short hh = f2bf(v[j]);
        h[j] = hh;
        l[j] = f2bf(v[j] - bf2f(hh));
    }
    *(bs8*)(hi + i) = h;
    *(bs8*)(lo + i) = l;
}

// ---------------------------------------------------------------------------
// spk_id + gather sel0 (fp32 + bf16 + into xg[:, F:])
// ---------------------------------------------------------------------------
__global__ __launch_bounds__(256) void k_gather(const float* __restrict__ mask,
                                                const float* __restrict__ sp0,
                                                int* __restrict__ spk,
                                                float* __restrict__ sel0,
                                                short* __restrict__ sel0_bf,
                                                short* __restrict__ xg) {
    int b = blockIdx.x, tid = threadIdx.x;
    __shared__ int sid;
    if (tid == 0) {
        int best = 0; float bv = mask[b * PP];
        for (int p = 1; p < PP; ++p) { float v = mask[b * PP + p]; if (v > bv) { bv = v; best = p; } }
        sid = best; spk[b] = best;
    }
    __syncthreads();
    const float* src = sp0 + ((size_t)b * PP + sid) * SS;
    for (int j = tid; j < SS; j += 256) {
        float v = src[j];
        sel0[(size_t)b * SS + j] = v;
        short h = f2bf(v);
        sel0_bf[(size_t)b * SS + j] = h;
        xg[(size_t)b * 1536 + FF + j] = h;
    }
}

// ---------------------------------------------------------------------------
// bf16 MFMA GEMM: C(M,N) = A(M,K) @ W(N,K)^T, fp32 out.
// 64x64 tile, 4 waves (2x2), each wave 32x32 via 2x2 mfma_f32_16x16x32_bf16.
// ---------------------------------------------------------------------------
__global__ __launch_bounds__(256) void k_gemm(const short* __restrict__ A, int lda,
                                              const short* __restrict__ W, int ldw,
                                              float* __restrict__ C, int ldc, int K) {
    __shared__ __align__(16) short As[64 * 64];
    __shared__ __align__(16) short Bs[64 * 64];
    const int tid = threadIdx.x;
    const int bm = blockIdx.y * 64, bn = blockIdx.x * 64;
    const int lane = tid & 63, wid = tid >> 6;
    const int wr = wid >> 1, wc = wid & 1;
    const int r0 = tid >> 3, c0 = tid & 7;
    const int r1 = r0 + 32;
    const int la = lane & 15, lk = lane >> 4;
    const int sw = la & 7;

    f32x4 acc[2][2] = {};

    for (int k0 = 0; k0 < K; k0 += 64) {
        bs8 va0 = *(const bs8*)(A + (size_t)(bm + r0) * lda + k0 + c0 * 8);
        bs8 va1 = *(const bs8*)(A + (size_t)(bm + r1) * lda + k0 + c0 * 8);
        bs8 vb0 = *(const bs8*)(W + (size_t)(bn + r0) * ldw + k0 + c0 * 8);
        bs8 vb1 = *(const bs8*)(W + (size_t)(bn + r1) * ldw + k0 + c0 * 8);
        __syncthreads();
        *(bs8*)(As + r0 * 64 + ((c0 ^ (r0 & 7)) * 8)) = va0;
        *(bs8*)(As + r1 * 64 + ((c0 ^ (r1 & 7)) * 8)) = va1;
        *(bs8*)(Bs + r0 * 64 + ((c0 ^ (r0 & 7)) * 8)) = vb0;
        *(bs8*)(Bs + r1 * 64 + ((c0 ^ (r1 & 7)) * 8)) = vb1;
        __syncthreads();
#pragma unroll
        for (int kk = 0; kk < 2; ++kk) {
            int slot = kk * 4 + lk;
            int off = (slot ^ sw) * 8;
            bs8 a0 = *(const bs8*)(As + (wr * 32 + la) * 64      + off);
            bs8 a1 = *(const bs8*)(As + (wr * 32 + 16 + la) * 64 + off);
            bs8 b0 = *(const bs8*)(Bs + (wc * 32 + la) * 64      + off);
            bs8 b1 = *(const bs8*)(Bs + (wc * 32 + 16 + la) * 64 + off);
            acc[0][0] = __builtin_amdgcn_mfma_f32_16x16x32_bf16(a0, b0, acc[0][0], 0, 0, 0);
            acc[0][1] = __builtin_amdgcn_mfma_f32_16x16x32_bf16(a0, b1, acc[0][1], 0, 0, 0);
            acc[1][0] = __builtin_amdgcn_mfma_f32_16x16x32_bf16(a1, b0, acc[1][0], 0, 0, 0);
            acc[1][1] = __builtin_amdgcn_mfma_f32_16x16x32_bf16(a1, b1, acc[1][1], 0, 0, 0);
        }
    }

    const int rowb = (lane >> 4) * 4, coln = lane & 15;
#pragma unroll
    for (int i = 0; i < 2; ++i)
#pragma unroll
    for (int j = 0; j < 2; ++j)
#pragma unroll
    for (int r = 0; r < 4; ++r) {
        int row = bm + wr * 32 + i * 16 + rowb + r;
        int col = bn + wc * 32 + j * 16 + coln;
        C[(size_t)row * ldc + col] = acc[i][j][r];
    }
}

// ---------------------------------------------------------------------------
// Split-precision GEMM: C = (Ah+Al) @ (Wh+Wl)^T dropping Al*Wl.
// Same geometry as k_gemm; 3 MFMAs per fragment pair.
// ---------------------------------------------------------------------------
__global__ __launch_bounds__(256) void k_gemm_split(
        const short* __restrict__ Ah, const short* __restrict__ Al, int lda,
        const short* __restrict__ Wh, const short* __restrict__ Wl, int ldw,
        float* __restrict__ C, int ldc, int K) {
    __shared__ __align__(16) short Ash[64 * 64], Asl[64 * 64];
    __shared__ __align__(16) short Bsh[64 * 64], Bsl[64 * 64];
    const int tid = threadIdx.x;
    const int bm = blockIdx.y * 64, bn = blockIdx.x * 64;
    const int lane = tid & 63, wid = tid >> 6;
    const int wr = wid >> 1, wc = wid & 1;
    const int r0 = tid >> 3, c0 = tid & 7;
    const int r1 = r0 + 32;
    const int la = lane & 15, lk = lane >> 4;
    const int sw = la & 7;

    f32x4 acc[2][2] = {};

    for (int k0 = 0; k0 < K; k0 += 64) {
        bs8 vah0 = *(const bs8*)(Ah + (size_t)(bm + r0) * lda + k0 + c0 * 8);
        bs8 vah1 = *(const bs8*)(Ah + (size_t)(bm + r1) * lda + k0 + c0 * 8);
        bs8 val0 = *(const bs8*)(Al + (size_t)(bm + r0) * lda + k0 + c0 * 8);
        bs8 val1 = *(const bs8*)(Al + (size_t)(bm + r1) * lda + k0 + c0 * 8);
        bs8 vbh0 = *(const bs8*)(Wh + (size_t)(bn + r0) * ldw + k0 + c0 * 8);
        bs8 vbh1 = *(const bs8*)(Wh + (size_t)(bn + r1) * ldw + k0 + c0 * 8);
        bs8 vbl0 = *(const bs8*)(Wl + (size_t)(bn + r0) * ldw + k0 + c0 * 8);
        bs8 vbl1 = *(const bs8*)(Wl + (size_t)(bn + r1) * ldw + k0 + c0 * 8);
        __syncthreads();
        *(bs8*)(Ash + r0 * 64 + ((c0 ^ (r0 & 7)) * 8)) = vah0;
        *(bs8*)(Ash + r1 * 64 + ((c0 ^ (r1 & 7)) * 8)) = vah1;
        *(bs8*)(Asl + r0 * 64 + ((c0 ^ (r0 & 7)) * 8)) = val0;
        *(bs8*)(Asl + r1 * 64 + ((c0 ^ (r1 & 7)) * 8)) = val1;
        *(bs8*)(Bsh + r0 * 64 + ((c0 ^ (r0 & 7)) * 8)) = vbh0;
        *(bs8*)(Bsh + r1 * 64 + ((c0 ^ (r1 & 7)) * 8)) = vbh1;
        *(bs8*)(Bsl + r0 * 64 + ((c0 ^ (r0 & 7)) * 8)) = vbl0;
        *(bs8*)(Bsl + r1 * 64 + ((c0 ^ (r1 & 7)) * 8)) = vbl1;
        __syncthreads();
#pragma unroll
        for (int kk = 0; kk < 2; ++kk) {
            int slot = kk * 4 + lk;
            int off = (slot ^ sw) * 8;
            bs8 ah0 = *(const bs8*)(Ash + (wr * 32 + la) * 64      + off);
            bs8 ah1 = *(const bs8*)(Ash + (wr * 32 + 16 + la) * 64 + off);
            bs8 al0 = *(const bs8*)(Asl + (wr * 32 + la) * 64      + off);
            bs8 al1 = *(const bs8*)(Asl + (wr * 32 + 16 + la) * 64 + off);
            bs8 bh0 = *(const bs8*)(Bsh + (wc * 32 + la) * 64      + off);
            bs8 bh1 = *(const bs8*)(Bsh + (wc * 32 + 16 + la) * 64 + off);
            bs8 bl0 = *(const bs8*)(Bsl + (wc * 32 + la) * 64      + off);
            bs8 bl1 = *(const bs8*)(Bsl + (wc * 32 + 16 + la) * 64 + off);
            acc[0][0] = __builtin_amdgcn_mfma_f32_16x16x32_bf16(ah0, bh0, acc[0][0], 0, 0, 0);
            acc[0][0] = __builtin_amdgcn_mfma_f32_16x16x32_bf16(ah0, bl0, acc[0][0], 0, 0, 0);
            acc[0][0] = __builtin_amdgcn_mfma_f32_16x16x32_bf16(al0, bh0, acc[0][0], 0, 0, 0);
            acc[0][1] = __builtin_amdgcn_mfma_f32_16x16x32_bf16(ah0, bh1, acc[0][1], 0, 0, 0);
            acc[0][1] = __builtin_amdgcn_mfma_f32_16x16x32_bf16(ah0, bl1, acc[0][1], 0, 0, 0);
            acc[0][1] = __builtin_amdgcn_mfma_f32_16x16x32_bf16(al0, bh1, acc[0][1], 0, 0, 0);
            acc[1][0] = __builtin_amdgcn_mfma_f32_16x16x32_bf16(ah1, bh0, acc[1][0], 0, 0, 0);
            acc[1][0] = __builtin_amdgcn_mfma_f32_16x16x32_bf16(ah1, bl0, acc[1][0], 0, 0, 0);
            acc[1][0] = __builtin_amdgcn_mfma_f32_16x16x32_bf16(al1, bh0, acc[1][0], 0, 0, 0);
            acc[1][1] = __builtin_amdgcn_mfma_f32_16x16x32_bf16(ah1, bh1, acc[1][1], 0, 0, 0);
            acc[1][1] = __builtin_amdgcn_mfma_f32_16x16x32_bf16(ah1, bl1, acc[1][1], 0, 0, 0);
            acc[1][1] = __builtin_amdgcn_mfma_f32_16x16x32_bf16(al1, bh1, acc[1][1], 0, 0, 0);
        }
    }

    const int rowb = (lane >> 4) * 4, coln = lane & 15;
#pragma unroll
    for (int i = 0; i < 2; ++i)
#pragma unroll
    for (int j = 0; j < 2; ++j)
#pragma unroll
    for (int r = 0; r < 4; ++r) {
        int row = bm + wr * 32 + i * 16 + rowb + r;
        int col = bn + wc * 32 + j * 16 + coln;
        C[(size_t)row * ldc + col] = acc[i][j][r];
    }
}

// ---------------------------------------------------------------------------
// Attention scores: one wave per (b,t).
// ---------------------------------------------------------------------------
__global__ __launch_bounds__(256) void k_scores(const float* __restrict__ x_,
                                                const float* __restrict__ gh,
                                                float* __restrict__ scores) {
    int task = blockIdx.x * 4 + (threadIdx.x >> 6);
    int lane = threadIdx.x & 63;
    int b = task & (BB - 1), t = task >> 8;
    const float* row = gh + ((size_t)t * BB + b) * GG + lane * 8;
    const float* xb  = x_ + (size_t)b * GG + lane * 8;
    float4 v1 = *(const float4*)row;
    float4 v2 = *(const float4*)(row + 4);
    float4 x1 = *(const float4*)xb;
    float4 x2 = *(const float4*)(xb + 4);
    float p = v1.x*x1.x + v1.y*x1.y + v1.z*x1.z + v1.w*x1.w
            + v2.x*x2.x + v2.y*x2.y + v2.z*x2.z + v2.w*x2.w;
#pragma unroll
    for (int off = 32; off; off >>= 1) p += __shfl_xor(p, off);
    if (lane == 0) scores[b * TT + t] = p;
}

__global__ __launch_bounds__(256) void k_softmax(const float* __restrict__ scores,
                                                 float* __restrict__ alpha) {
    int b = blockIdx.x, tid = threadIdx.x;
    __shared__ float red[256];
    float v = scores[b * TT + tid];
    red[tid] = v; __syncthreads();
    for (int off = 128; off; off >>= 1) { if (tid < off) red[tid] = fmaxf(red[tid], red[tid + off]); __syncthreads(); }
    float m = red[0]; __syncthreads();
    float e = expf(v - m);
    red[tid] = e; __syncthreads();
    for (int off = 128; off; off >>= 1) { if (tid < off) red[tid] += red[tid + off]; __syncthreads(); }
    alpha[b * TT + tid] = e / red[0];
}

__global__ __launch_bounds__(1024) void k_ctx(const float* __restrict__ alpha,
                                              const float* __restrict__ gh,
                                              short* __restrict__ xp) {
    int b = blockIdx.x, tid = threadIdx.x;
    int w = tid >> 6, lane = tid & 63;
    __shared__ float part[16][GG];
    float acc[8] = {};
    for (int it = 0; it < 16; ++it) {
        int t = w * 16 + it;
        float a = alpha[b * TT + t];
        const float* row = gh + ((size_t)t * BB + b) * GG + lane * 8;
        float4 v1 = *(const float4*)row;
        float4 v2 = *(const float4*)(row + 4);
        acc[0] += a * v1.x; acc[1] += a * v1.y; acc[2] += a * v1.z; acc[3] += a * v1.w;
        acc[4] += a * v2.x; acc[5] += a * v2.y; acc[6] += a * v2.z; acc[7] += a * v2.w;
    }
#pragma unroll
    for (int e = 0; e < 8; ++e) part[w][lane * 8 + e] = acc[e];
    __syncthreads();
    if (tid < GG) {
        float s = 0.f;
#pragma unroll
        for (int w2 = 0; w2 < 16; ++w2) s += part[w2][tid];
        xp[(size_t)b * 1536 + FF + tid] = f2bf(s);
    }
}

// ---------------------------------------------------------------------------
__global__ __launch_bounds__(256) void k_gru(const float* __restrict__ gi, const float* __restrict__ gh,
                                             const float* __restrict__ bih, const float* __restrict__ bhh,
                                             const float* __restrict__ h,
                                             float* __restrict__ out, short* __restrict__ out_bf, int H) {
    int idx = blockIdx.x * 256 + threadIdx.x;
    int b = idx / H, j = idx - b * H;
    const float* gib = gi + (size_t)b * 3 * H;
    const float* ghb = gh + (size_t)b * 3 * H;
    float r = sigmoidf_(gib[j] + bih[j] + ghb[j] + bhh[j]);
    float z = sigmoidf_(gib[H + j] + bih[H + j] + ghb[H + j] + bhh[H + j]);
    float n = tanhf(gib[2 * H + j] + bih[2 * H + j] + r * (ghb[2 * H + j] + bhh[2 * H + j]));
    float o = (1.0f - z) * n + z * h[idx];
    out[idx] = o;
    if (out_bf) out_bf[idx] = f2bf(o);
}

__global__ __launch_bounds__(256) void k_speaker(const float* __restrict__ speaker0,
                                                 const float* __restrict__ parties,
                                                 const int* __restrict__ spk,
                                                 float* __restrict__ out) {
    int idx = blockIdx.x * 256 + threadIdx.x;
    int s = idx & (SS - 1);
    int p = (idx / SS) & (PP - 1);
    int b = idx / (SS * PP);
    float v = speaker0[idx];
    if (p == spk[b]) v = parties[(size_t)b * SS + s];
    out[idx] = v;
}

// ---------------------------------------------------------------------------
static inline void gemm(hipStream_t st, const short* A, int lda, const short* W, int ldw,
                        float* C, int N, int K) {
    dim3 g(N / 64, BB / 64);
    k_gemm<<<g, 256, 0, st>>>(A, lda, W, ldw, C, N, K);
}

extern "C" void kernel_launch(void* const* d_in, const int* in_sizes, int n_in,
                              void* d_out, int out_size, void* d_ws, size_t ws_size,
                              hipStream_t stream) {
    const float* feature_ = (const float*)d_in[0];
    const float* mask     = (const float*)d_in[1];
    const float* ghist    = (const float*)d_in[2];
    const float* speaker0 = (const float*)d_in[3];
    const float* emotion0 = (const float*)d_in[4];
    const float* Wg_ih    = (const float*)d_in[5];
    const float* Wg_hh    = (const float*)d_in[6];
    const float* bg_ih    = (const float*)d_in[7];
    const float* bg_hh    = (const float*)d_in[8];
    const float* Wp_ih    = (const float*)d_in[9];
    const float* Wp_hh    = (const float*)d_in[10];
    const float* bp_ih    = (const float*)d_in[11];
    const float* bp_hh    = (const float*)d_in[12];
    const float* We_ih    = (const float*)d_in[13];
    const float* We_hh    = (const float*)d_in[14];
    const float* be_ih    = (const float*)d_in[15];
    const float* be_hh    = (const float*)d_in[16];
    const float* attn_W   = (const float*)d_in[17];

    float* out = (float*)d_out;
    float* emotion_out = out;
    float* global_out  = out + (size_t)BB * EE;
    float* speaker_out = global_out + (size_t)BB * GG;

    char* cur = (char*)d_ws;
    short* Wbf = (short*)cur;              cur += (size_t)WTOT * 2;
    short* Wg_ih_bf  = Wbf;
    short* Wg_hh_bf  = Wbf + W0E;
    short* Wp_ih_bf  = Wbf + W0E + W1E;
    short* Wp_hh_bf  = Wbf + W0E + W1E + W2E;
    short* We_ih_bf  = Wbf + W0E + W1E + W2E + W3E;
    short* We_hh_bf  = Wbf + W0E + W1E + W2E + W3E + W4E;

    short* xg      = (short*)cur; cur += (size_t)BB * 1536 * 2;
    short* xp      = (short*)cur; cur += (size_t)BB * 1536 * 2;
    short* hg_bf   = (short*)cur; cur += (size_t)BB * GG * 2;
    short* sel0_bf = (short*)cur; cur += (size_t)BB * SS * 2;
    short* emo_bf  = (short*)cur; cur += (size_t)BB * EE * 2;
    short* par_bf  = (short*)cur; cur += (size_t)BB * SS * 2;
    short* fhi     = (short*)cur; cur += (size_t)BB * FF * 2;
    short* flo     = (short*)cur; cur += (size_t)BB * FF * 2;
    short* awhi    = (short*)cur; cur += (size_t)GG * FF * 2;
    short* awlo    = (short*)cur; cur += (size_t)GG * FF * 2;

    float* sel0    = (float*)cur; cur += (size_t)BB * SS * 4;
    float* x_      = (float*)cur; cur += (size_t)BB * GG * 4;
    float* scores  = (float*)cur; cur += (size_t)BB * TT * 4;
    float* alpha   = (float*)cur; cur += (size_t)BB * TT * 4;
    float* parties = (float*)cur; cur += (size_t)BB * SS * 4;
    float* gi_g    = (float*)cur; cur += (size_t)BB * 3 * GG * 4;
    float* gh_g    = (float*)cur; cur += (size_t)BB * 3 * GG * 4;
    float* gi_p    = (float*)cur; cur += (size_t)BB * 3 * SS * 4;
    float* gh_p    = (float*)cur; cur += (size_t)BB * 3 * SS * 4;
    float* gi_e    = (float*)cur; cur += (size_t)BB * 3 * EE * 4;
    float* gh_e    = (float*)cur; cur += (size_t)BB * 3 * EE * 4;
    int*   spk     = (int*)cur;   cur += 256 * 4;

    const float* h_g = ghist + (size_t)(TT - 1) * BB * GG;

    // ---- conversions
    k_convw<<<WTOT / 8 / 256, 256, 0, stream>>>(Wg_ih, Wg_hh, Wp_ih, Wp_hh, We_ih, We_hh, attn_W, Wbf);
    k_convf<<<(BB * FF) / 8 / 256, 256, 0, stream>>>(feature_, xg, xp);
    k_conv<<<(BB * GG) / 8 / 256, 256, 0, stream>>>(h_g, hg_bf, (BB * GG) / 8);
    k_conv<<<(BB * EE) / 8 / 256, 256, 0, stream>>>(emotion0, emo_bf, (BB * EE) / 8);
    k_convsplit<<<(BB * FF) / 8 / 256, 256, 0, stream>>>(feature_, fhi, flo, (BB * FF) / 8);
    k_convsplit<<<(GG * FF) / 8 / 256, 256, 0, stream>>>(attn_W, awhi, awlo, (GG * FF) / 8);
    k_gather<<<BB, 256, 0, stream>>>(mask, speaker0, spk, sel0, sel0_bf, xg);

    // ---- global GRU
    gemm(stream, xg, FF + SS, Wg_ih_bf, FF + SS, gi_g, 3 * GG, FF + SS);
    gemm(stream, hg_bf, GG, Wg_hh_bf, GG, gh_g, 3 * GG, GG);
    k_gru<<<(BB * GG) / 256, 256, 0, stream>>>(gi_g, gh_g, bg_ih, bg_hh, h_g, global_out, nullptr, GG);

    // ---- attention (split-precision x_ so softmax ordering matches fp32)
    {
        dim3 g(GG / 64, BB / 64);
        k_gemm_split<<<g, 256, 0, stream>>>(fhi, flo, FF, awhi, awlo, FF, x_, GG, FF);
    }
    k_scores<<<(BB * TT) / 4, 256, 0, stream>>>(x_, ghist, scores);
    k_softmax<<<BB, 256, 0, stream>>>(scores, alpha);
    k_ctx<<<BB, 1024, 0, stream>>>(alpha, ghist, xp);

    // ---- parties GRU (selected rows only)
    gemm(stream, xp, FF + GG, Wp_ih_bf, FF + GG, gi_p, 3 * SS, FF + GG);
    gemm(stream, sel0_bf, SS, Wp_hh_bf, SS, gh_p, 3 * SS, SS);
    k_gru<<<(BB * SS) / 256, 256, 0, stream>>>(gi_p, gh_p, bp_ih, bp_hh, sel0, parties, par_bf, SS);

    // ---- speaker output
    k_speaker<<<(BB * PP * SS) / 256, 256, 0, stream>>>(speaker0, parties, spk, speaker_out);

    // ---- emotion GRU
    gemm(stream, par_bf, SS, We_ih_bf, SS, gi_e, 3 * EE, SS);
    gemm(stream, emo_bf, EE, We_hh_bf, EE, gh_e, 3 * EE, EE);
    k_gru<<<(BB * EE) / 256, 256, 0, stream>>>(gi_e, gh_e, be_ih, be_hh, emotion0, emotion_out, nullptr, EE);
}

// Round 4
// 118.860 us; speedup vs baseline: 3.2279x; 1.2713x over previous
//
#include <hip/hip_runtime.h>
#include <math.h>

#define BB 256
#define FF 1024
#define GG 512
#define SS 512
#define EE 256
#define PP 8
#define TT 256

typedef __attribute__((ext_vector_type(8))) short bs8;     // 8 bf16
typedef __attribute__((ext_vector_type(4))) float f32x4;

__device__ __forceinline__ float sigmoidf_(float x) { return 1.0f / (1.0f + expf(-x)); }

__device__ __forceinline__ short f2bf(float f) {
    union { float f; unsigned u; } v; v.f = f;
    unsigned r = v.u + 0x7FFFu + ((v.u >> 16) & 1u);   // RNE
    return (short)(r >> 16);
}
__device__ __forceinline__ float bf2f(short h) {
    union { unsigned u; float f; } t; t.u = ((unsigned)(unsigned short)h) << 16; return t.f;
}

__device__ __forceinline__ bs8 ld8cvt(const float* p) {
    float4 a = *(const float4*)p, b = *(const float4*)(p + 4);
    bs8 o;
    o[0]=f2bf(a.x); o[1]=f2bf(a.y); o[2]=f2bf(a.z); o[3]=f2bf(a.w);
    o[4]=f2bf(b.x); o[5]=f2bf(b.y); o[6]=f2bf(b.z); o[7]=f2bf(b.w);
    return o;
}
__device__ __forceinline__ void ld8split(const float* p, bs8& h, bs8& l) {
    float4 a = *(const float4*)p, b = *(const float4*)(p + 4);
    float v[8] = {a.x, a.y, a.z, a.w, b.x, b.y, b.z, b.w};
#pragma unroll
    for (int j = 0; j < 8; ++j) {
        short hh = f2bf(v[j]);
        h[j] = hh;
        l[j] = f2bf(v[j] - bf2f(hh));
    }
}

// ---------------------------------------------------------------------------
// spk_id + gather sel0 (fp32)
// ---------------------------------------------------------------------------
__global__ __launch_bounds__(256) void k_gather(const float* __restrict__ mask,
                                                const float* __restrict__ sp0,
                                                int* __restrict__ spk,
                                                float* __restrict__ sel0) {
    int b = blockIdx.x, tid = threadIdx.x;
    __shared__ int sid;
    if (tid == 0) {
        int best = 0; float bv = mask[b * PP];
        for (int p = 1; p < PP; ++p) { float v = mask[b * PP + p]; if (v > bv) { bv = v; best = p; } }
        sid = best; spk[b] = best;
    }
    __syncthreads();
    const float* src = sp0 + ((size_t)b * PP + sid) * SS;
    sel0[(size_t)b * SS + tid]       = src[tid];
    sel0[(size_t)b * SS + tid + 256] = src[tid + 256];
}

// speaker0 -> speaker_out verbatim (selected rows overwritten later by gru_p)
__global__ __launch_bounds__(256) void k_spkcopy(const float* __restrict__ src, float* __restrict__ dst) {
    size_t i = ((size_t)blockIdx.x * 256 + threadIdx.x) * 4;
    *(float4*)(dst + i) = *(const float4*)(src + i);
}

// ---------------------------------------------------------------------------
// Batched bf16 MFMA GEMM over fp32 sources (in-register cvt during staging).
// C(M=256, N) = A(M,K) @ W(N, ldw)[:, woff:woff+K]^T
// flags: 1 = split hi/lo (3-MFMA compensated product), 2 = accumulate into C.
// A is split at column kb: k < kb reads A (lda), k >= kb reads A2 (lda2).
// 64x64 tile, 4 waves (2x2), wave = 32x32 via 2x2 mfma_f32_16x16x32_bf16.
// ---------------------------------------------------------------------------
struct GDesc {
    const float *A, *A2, *W;
    float* C;
    int lda, lda2, kb, ldw, woff, ldc, K, nbn, flags;
};
struct GBatch {
    GDesc d[6];
    int start[7];
    int ng;
};

__global__ __launch_bounds__(256) void k_bgemm(GBatch gb) {
    __shared__ __align__(16) short Ash[64 * 64], Bsh[64 * 64];
    __shared__ __align__(16) short Asl[64 * 64], Bsl[64 * 64];

    int bid = blockIdx.x;
    int g = 0;
    while (g + 1 < gb.ng && bid >= gb.start[g + 1]) ++g;
    GDesc d = gb.d[g];
    int local = bid - gb.start[g];
    int bn = local % d.nbn, bm = local / d.nbn;
    const bool split = (d.flags & 1) != 0;

    const int tid = threadIdx.x;
    const int lane = tid & 63, wid = tid >> 6;
    const int wr = wid >> 1, wc = wid & 1;
    const int r0 = tid >> 3, c0 = tid & 7;
    const int r1 = r0 + 32;
    const int la = lane & 15, lk = lane >> 4;
    const int sw = la & 7;

    f32x4 acc[2][2] = {};

    for (int k0 = 0; k0 < d.K; k0 += 64) {
        const float* Ab; int alda;
        if (k0 < d.kb) { Ab = d.A + k0; alda = d.lda; }
        else           { Ab = d.A2 + (k0 - d.kb); alda = d.lda2; }
        const float* pa0 = Ab + (size_t)(bm * 64 + r0) * alda + c0 * 8;
        const float* pa1 = Ab + (size_t)(bm * 64 + r1) * alda + c0 * 8;
        const float* pw0 = d.W + (size_t)(bn * 64 + r0) * d.ldw + d.woff + k0 + c0 * 8;
        const float* pw1 = d.W + (size_t)(bn * 64 + r1) * d.ldw + d.woff + k0 + c0 * 8;

        bs8 ah0, ah1, bh0, bh1, al0, al1, bl0, bl1;
        if (split) {
            ld8split(pa0, ah0, al0); ld8split(pa1, ah1, al1);
            ld8split(pw0, bh0, bl0); ld8split(pw1, bh1, bl1);
        } else {
            ah0 = ld8cvt(pa0); ah1 = ld8cvt(pa1);
            bh0 = ld8cvt(pw0); bh1 = ld8cvt(pw1);
        }
        __syncthreads();   // previous iteration's LDS reads done
        *(bs8*)(Ash + r0 * 64 + ((c0 ^ (r0 & 7)) * 8)) = ah0;
        *(bs8*)(Ash + r1 * 64 + ((c0 ^ (r1 & 7)) * 8)) = ah1;
        *(bs8*)(Bsh + r0 * 64 + ((c0 ^ (r0 & 7)) * 8)) = bh0;
        *(bs8*)(Bsh + r1 * 64 + ((c0 ^ (r1 & 7)) * 8)) = bh1;
        if (split) {
            *(bs8*)(Asl + r0 * 64 + ((c0 ^ (r0 & 7)) * 8)) = al0;
            *(bs8*)(Asl + r1 * 64 + ((c0 ^ (r1 & 7)) * 8)) = al1;
            *(bs8*)(Bsl + r0 * 64 + ((c0 ^ (r0 & 7)) * 8)) = bl0;
            *(bs8*)(Bsl + r1 * 64 + ((c0 ^ (r1 & 7)) * 8)) = bl1;
        }
        __syncthreads();
#pragma unroll
        for (int kk = 0; kk < 2; ++kk) {
            int slot = kk * 4 + lk;
            int off = (slot ^ sw) * 8;
            bs8 a0 = *(const bs8*)(Ash + (wr * 32 + la) * 64      + off);
            bs8 a1 = *(const bs8*)(Ash + (wr * 32 + 16 + la) * 64 + off);
            bs8 b0 = *(const bs8*)(Bsh + (wc * 32 + la) * 64      + off);
            bs8 b1 = *(const bs8*)(Bsh + (wc * 32 + 16 + la) * 64 + off);
            acc[0][0] = __builtin_amdgcn_mfma_f32_16x16x32_bf16(a0, b0, acc[0][0], 0, 0, 0);
            acc[0][1] = __builtin_amdgcn_mfma_f32_16x16x32_bf16(a0, b1, acc[0][1], 0, 0, 0);
            acc[1][0] = __builtin_amdgcn_mfma_f32_16x16x32_bf16(a1, b0, acc[1][0], 0, 0, 0);
            acc[1][1] = __builtin_amdgcn_mfma_f32_16x16x32_bf16(a1, b1, acc[1][1], 0, 0, 0);
            if (split) {
                bs8 xl0 = *(const bs8*)(Asl + (wr * 32 + la) * 64      + off);
                bs8 xl1 = *(const bs8*)(Asl + (wr * 32 + 16 + la) * 64 + off);
                bs8 yl0 = *(const bs8*)(Bsl + (wc * 32 + la) * 64      + off);
                bs8 yl1 = *(const bs8*)(Bsl + (wc * 32 + 16 + la) * 64 + off);
                acc[0][0] = __builtin_amdgcn_mfma_f32_16x16x32_bf16(a0, yl0, acc[0][0], 0, 0, 0);
                acc[0][0] = __builtin_amdgcn_mfma_f32_16x16x32_bf16(xl0, b0, acc[0][0], 0, 0, 0);
                acc[0][1] = __builtin_amdgcn_mfma_f32_16x16x32_bf16(a0, yl1, acc[0][1], 0, 0, 0);
                acc[0][1] = __builtin_amdgcn_mfma_f32_16x16x32_bf16(xl0, b1, acc[0][1], 0, 0, 0);
                acc[1][0] = __builtin_amdgcn_mfma_f32_16x16x32_bf16(a1, yl0, acc[1][0], 0, 0, 0);
                acc[1][0] = __builtin_amdgcn_mfma_f32_16x16x32_bf16(xl1, b0, acc[1][0], 0, 0, 0);
                acc[1][1] = __builtin_amdgcn_mfma_f32_16x16x32_bf16(a1, yl1, acc[1][1], 0, 0, 0);
                acc[1][1] = __builtin_amdgcn_mfma_f32_16x16x32_bf16(xl1, b1, acc[1][1], 0, 0, 0);
            }
        }
    }

    const int rowb = (lane >> 4) * 4, coln = lane & 15;
    const bool accum = (d.flags & 2) != 0;
#pragma unroll
    for (int i = 0; i < 2; ++i)
#pragma unroll
    for (int j = 0; j < 2; ++j)
#pragma unroll
    for (int r = 0; r < 4; ++r) {
        int row = bm * 64 + wr * 32 + i * 16 + rowb + r;
        int col = bn * 64 + wc * 32 + j * 16 + coln;
        size_t idx = (size_t)row * d.ldc + col;
        if (accum) d.C[idx] += acc[i][j][r];
        else       d.C[idx]  = acc[i][j][r];
    }
}

// ---------------------------------------------------------------------------
// Attention scores: one wave per (b,t).
// ---------------------------------------------------------------------------
__global__ __launch_bounds__(256) void k_scores(const float* __restrict__ x_,
                                                const float* __restrict__ gh,
                                                float* __restrict__ scores) {
    int task = blockIdx.x * 4 + (threadIdx.x >> 6);
    int lane = threadIdx.x & 63;
    int b = task & (BB - 1), t = task >> 8;
    const float* row = gh + ((size_t)t * BB + b) * GG + lane * 8;
    const float* xb  = x_ + (size_t)b * GG + lane * 8;
    float4 v1 = *(const float4*)row;
    float4 v2 = *(const float4*)(row + 4);
    float4 x1 = *(const float4*)xb;
    float4 x2 = *(const float4*)(xb + 4);
    float p = v1.x*x1.x + v1.y*x1.y + v1.z*x1.z + v1.w*x1.w
            + v2.x*x2.x + v2.y*x2.y + v2.z*x2.z + v2.w*x2.w;
#pragma unroll
    for (int off = 32; off; off >>= 1) p += __shfl_xor(p, off);
    if (lane == 0) scores[b * TT + t] = p;
}

// ---------------------------------------------------------------------------
// Fused softmax (over T per b) + context accumulation; ctx fp32 out.
// ---------------------------------------------------------------------------
__global__ __launch_bounds__(1024) void k_softctx(const float* __restrict__ scores,
                                                  const float* __restrict__ gh,
                                                  float* __restrict__ ctx) {
    int b = blockIdx.x, tid = threadIdx.x;
    __shared__ float sal[TT];
    __shared__ float red[TT];
    __shared__ float part[16][GG];

    float v = 0.f;
    if (tid < TT) { v = scores[b * TT + tid]; red[tid] = v; }
    __syncthreads();
    for (int off = 128; off; off >>= 1) {
        if (tid < off) red[tid] = fmaxf(red[tid], red[tid + off]);
        __syncthreads();
    }
    float m = red[0];
    __syncthreads();
    float e = 0.f;
    if (tid < TT) { e = expf(v - m); red[tid] = e; }
    __syncthreads();
    for (int off = 128; off; off >>= 1) {
        if (tid < off) red[tid] += red[tid + off];
        __syncthreads();
    }
    if (tid < TT) sal[tid] = e / red[0];
    __syncthreads();

    int w = tid >> 6, lane = tid & 63;
    float acc[8] = {};
    for (int it = 0; it < 16; ++it) {
        int t = w * 16 + it;
        float a = sal[t];
        const float* row = gh + ((size_t)t * BB + b) * GG + lane * 8;
        float4 v1 = *(const float4*)row;
        float4 v2 = *(const float4*)(row + 4);
        acc[0] += a * v1.x; acc[1] += a * v1.y; acc[2] += a * v1.z; acc[3] += a * v1.w;
        acc[4] += a * v2.x; acc[5] += a * v2.y; acc[6] += a * v2.z; acc[7] += a * v2.w;
    }
#pragma unroll
    for (int e2 = 0; e2 < 8; ++e2) part[w][lane * 8 + e2] = acc[e2];
    __syncthreads();
    if (tid < GG) {
        float s = 0.f;
#pragma unroll
        for (int w2 = 0; w2 < 16; ++w2) s += part[w2][tid];
        ctx[(size_t)b * GG + tid] = s;
    }
}

// ---------------------------------------------------------------------------
// GRU elementwise (biases folded here). Plain variant writes out only.
// ---------------------------------------------------------------------------
__global__ __launch_bounds__(256) void k_gru(const float* __restrict__ gi, const float* __restrict__ gh,
                                             const float* __restrict__ bih, const float* __restrict__ bhh,
                                             const float* __restrict__ h,
                                             float* __restrict__ out, int H) {
    int idx = blockIdx.x * 256 + threadIdx.x;
    int b = idx / H, j = idx - b * H;
    const float* gib = gi + (size_t)b * 3 * H;
    const float* ghb = gh + (size_t)b * 3 * H;
    float r = sigmoidf_(gib[j] + bih[j] + ghb[j] + bhh[j]);
    float z = sigmoidf_(gib[H + j] + bih[H + j] + ghb[H + j] + bhh[H + j]);
    float n = tanhf(gib[2 * H + j] + bih[2 * H + j] + r * (ghb[2 * H + j] + bhh[2 * H + j]));
    out[idx] = (1.0f - z) * n + z * h[idx];
}

// parties variant: writes parties AND scatters into speaker_out[b, spk[b], :]
__global__ __launch_bounds__(256) void k_gru_spk(const float* __restrict__ gi, const float* __restrict__ gh,
                                                 const float* __restrict__ bih, const float* __restrict__ bhh,
                                                 const float* __restrict__ h,
                                                 const int* __restrict__ spk,
                                                 float* __restrict__ parties,
                                                 float* __restrict__ speaker_out) {
    int idx = blockIdx.x * 256 + threadIdx.x;
    int b = idx / SS, j = idx - b * SS;
    const float* gib = gi + (size_t)b * 3 * SS;
    const float* ghb = gh + (size_t)b * 3 * SS;
    float r = sigmoidf_(gib[j] + bih[j] + ghb[j] + bhh[j]);
    float z = sigmoidf_(gib[SS + j] + bih[SS + j] + ghb[SS + j] + bhh[SS + j]);
    float n = tanhf(gib[2 * SS + j] + bih[2 * SS + j] + r * (ghb[2 * SS + j] + bhh[2 * SS + j]));
    float o = (1.0f - z) * n + z * h[idx];
    parties[idx] = o;
    speaker_out[((size_t)b * PP + spk[b]) * SS + j] = o;
}

// ---------------------------------------------------------------------------
extern "C" void kernel_launch(void* const* d_in, const int* in_sizes, int n_in,
                              void* d_out, int out_size, void* d_ws, size_t ws_size,
                              hipStream_t stream) {
    const float* feature_ = (const float*)d_in[0];
    const float* mask     = (const float*)d_in[1];
    const float* ghist    = (const float*)d_in[2];
    const float* speaker0 = (const float*)d_in[3];
    const float* emotion0 = (const float*)d_in[4];
    const float* Wg_ih    = (const float*)d_in[5];
    const float* Wg_hh    = (const float*)d_in[6];
    const float* bg_ih    = (const float*)d_in[7];
    const float* bg_hh    = (const float*)d_in[8];
    const float* Wp_ih    = (const float*)d_in[9];
    const float* Wp_hh    = (const float*)d_in[10];
    const float* bp_ih    = (const float*)d_in[11];
    const float* bp_hh    = (const float*)d_in[12];
    const float* We_ih    = (const float*)d_in[13];
    const float* We_hh    = (const float*)d_in[14];
    const float* be_ih    = (const float*)d_in[15];
    const float* be_hh    = (const float*)d_in[16];
    const float* attn_W   = (const float*)d_in[17];

    float* out = (float*)d_out;
    float* emotion_out = out;
    float* global_out  = out + (size_t)BB * EE;
    float* speaker_out = global_out + (size_t)BB * GG;

    char* cur = (char*)d_ws;
    float* sel0    = (float*)cur; cur += (size_t)BB * SS * 4;
    float* x_      = (float*)cur; cur += (size_t)BB * GG * 4;
    float* scores  = (float*)cur; cur += (size_t)BB * TT * 4;
    float* ctx     = (float*)cur; cur += (size_t)BB * GG * 4;
    float* parties = (float*)cur; cur += (size_t)BB * SS * 4;
    float* gi_g    = (float*)cur; cur += (size_t)BB * 3 * GG * 4;
    float* gh_g    = (float*)cur; cur += (size_t)BB * 3 * GG * 4;
    float* gi_p    = (float*)cur; cur += (size_t)BB * 3 * SS * 4;
    float* gh_p    = (float*)cur; cur += (size_t)BB * 3 * SS * 4;
    float* gi_e    = (float*)cur; cur += (size_t)BB * 3 * EE * 4;
    float* gh_e    = (float*)cur; cur += (size_t)BB * 3 * EE * 4;
    int*   spk     = (int*)cur;   cur += 256 * 4;

    const float* h_g = ghist + (size_t)(TT - 1) * BB * GG;

    // 1) gather + speaker bulk copy
    k_gather<<<BB, 256, 0, stream>>>(mask, speaker0, spk, sel0);
    k_spkcopy<<<(BB * PP * SS) / 4 / 256, 256, 0, stream>>>(speaker0, speaker_out);

    // 2) phase-1 batched GEMMs (everything not needing attention output)
    GBatch gb1;
    // gi_g = [feature|sel0] @ Wg_ih^T            (N=1536, K=1536)
    gb1.d[0] = { feature_, sel0, Wg_ih, gi_g, FF, SS, FF, FF + SS, 0, 3 * GG, FF + SS, 24, 0 };
    // gh_g = h_g @ Wg_hh^T                       (N=1536, K=512)
    gb1.d[1] = { h_g, h_g, Wg_hh, gh_g, GG, GG, GG, GG, 0, 3 * GG, GG, 24, 0 };
    // x_ = feature @ attn_W^T  (split hi/lo)     (N=512, K=1024)
    gb1.d[2] = { feature_, feature_, attn_W, x_, FF, FF, FF, FF, 0, GG, FF, 8, 1 };
    // gh_p = sel0 @ Wp_hh^T                      (N=1536, K=512)
    gb1.d[3] = { sel0, sel0, Wp_hh, gh_p, SS, SS, SS, SS, 0, 3 * SS, SS, 24, 0 };
    // gh_e = emotion0 @ We_hh^T                  (N=768, K=256)
    gb1.d[4] = { emotion0, emotion0, We_hh, gh_e, EE, EE, EE, EE, 0, 3 * EE, EE, 12, 0 };
    // gi_p (feature half) = feature @ Wp_ih[:, :F]^T   (N=1536, K=1024)
    gb1.d[5] = { feature_, feature_, Wp_ih, gi_p, FF, FF, FF, FF + GG, 0, 3 * SS, FF, 24, 0 };
    gb1.start[0] = 0;   gb1.start[1] = 96;  gb1.start[2] = 192; gb1.start[3] = 224;
    gb1.start[4] = 320; gb1.start[5] = 368; gb1.start[6] = 464;
    gb1.ng = 6;
    k_bgemm<<<464, 256, 0, stream>>>(gb1);

    // 3) global GRU output
    k_gru<<<(BB * GG) / 256, 256, 0, stream>>>(gi_g, gh_g, bg_ih, bg_hh, h_g, global_out, GG);

    // 4) attention
    k_scores<<<(BB * TT) / 4, 256, 0, stream>>>(x_, ghist, scores);
    k_softctx<<<BB, 1024, 0, stream>>>(scores, ghist, ctx);

    // 5) gi_p += ctx @ Wp_ih[:, F:]^T   (N=1536, K=512, accumulate)
    GBatch gb2;
    gb2.d[0] = { ctx, ctx, Wp_ih, gi_p, GG, GG, GG, FF + GG, FF, 3 * SS, GG, 24, 2 };
    gb2.start[0] = 0; gb2.start[1] = 96; gb2.ng = 1;
    k_bgemm<<<96, 256, 0, stream>>>(gb2);

    // 6) parties GRU + scatter into speaker_out
    k_gru_spk<<<(BB * SS) / 256, 256, 0, stream>>>(gi_p, gh_p, bp_ih, bp_hh, sel0, spk, parties, speaker_out);

    // 7) gi_e = parties @ We_ih^T   (N=768, K=512)
    GBatch gb3;
    gb3.d[0] = { parties, parties, We_ih, gi_e, SS, SS, SS, SS, 0, 3 * EE, SS, 12, 0 };
    gb3.start[0] = 0; gb3.start[1] = 48; gb3.ng = 1;
    k_bgemm<<<48, 256, 0, stream>>>(gb3);

    // 8) emotion GRU
    k_gru<<<(BB * EE) / 256, 256, 0, stream>>>(gi_e, gh_e, be_ih, be_hh, emotion0, emotion_out, EE);
}